// Round 12
// baseline (362.983 us; speedup 1.0000x reference)
//
#include <hip/hip_runtime.h>

#define HW    3136
#define HDIM  56
#define CIN   256
#define CR    64
#define NG    16
#define KK    49
#define BEPS  1e-5f
#define RB    2            // output rows per k2 band
#define NBAND 28           // 56 / RB
#define WSTR  116          // w_lds row stride (RB*56 + 4 floats)

typedef __attribute__((ext_vector_type(8))) short short8;
typedef __attribute__((ext_vector_type(4))) float f32x4;

__device__ __forceinline__ unsigned short f2bf(float f) {
    union { float f; unsigned u; } v; v.f = f;
    unsigned r = (v.u + 0x7FFFu + ((v.u >> 16) & 1u)) >> 16;
    return (unsigned short)r;
}

// k0: W1b[o][c]=bf16(W1*scale) (B^T for k1); W2bT[g][tap pad64][c]=bf16(W2)
//     (B^T for k2 phase A); b1f = folded BN bias.
__global__ __launch_bounds__(256) void k0_prep(
    const float* __restrict__ W1, const float* __restrict__ b1,
    const float* __restrict__ gamma, const float* __restrict__ beta,
    const float* __restrict__ mean, const float* __restrict__ var,
    const float* __restrict__ W2,
    unsigned short* __restrict__ W1b, unsigned short* __restrict__ W2bT,
    float* __restrict__ b1f)
{
    int idx = blockIdx.x * 256 + threadIdx.x;
    if (idx < CR * CIN) {
        int o = idx >> 8;
        float s = gamma[o] * rsqrtf(var[o] + BEPS);
        W1b[idx] = f2bf(W1[idx] * s);
    } else if (idx < CR * CIN + NG * 64 * 64) {
        int j = idx - CR * CIN;
        int c = j & 63, tap = (j >> 6) & 63, g = j >> 12;
        float v = (tap < KK) ? W2[(g * KK + tap) * CR + c] : 0.f;
        W2bT[j] = f2bf(v);
    } else if (idx < CR * CIN + NG * 64 * 64 + CR) {
        int o = idx - CR * CIN - NG * 64 * 64;
        float s = gamma[o] * rsqrtf(var[o] + BEPS);
        b1f[o] = b1[o] * s + beta[o] - mean[o] * s;
    }
}

// k1: conv1 MFMA, LDS-free (r8-identical). Wave = 16px M-tile x 64 outs, K=256.
__global__ __launch_bounds__(256) void k1_gemm(
    const float* __restrict__ x, const unsigned short* __restrict__ W1b,
    const float* __restrict__ b1f, unsigned short* __restrict__ t_bf)
{
    const int tid = threadIdx.x;
    const int b = blockIdx.y;
    const int lane = tid & 63, l15 = lane & 15, q = lane >> 4;
    const int wid = tid >> 6;
    const int pxb = blockIdx.x * 64 + wid * 16;

    const float* xp = x + (size_t)b * CIN * HW + pxb + l15;

    f32x4 acc[4];
#pragma unroll
    for (int nt = 0; nt < 4; nt++) acc[nt] = (f32x4){0.f, 0.f, 0.f, 0.f};

#pragma unroll 2
    for (int kc = 0; kc < 8; kc++) {
        short8 af;
#pragma unroll
        for (int j = 0; j < 8; j++) {
            float xv = xp[(size_t)(kc * 32 + q * 8 + j) * HW];
            af[j] = (short)f2bf(xv);
        }
#pragma unroll
        for (int nt = 0; nt < 4; nt++) {
            short8 bf = *(const short8*)&W1b[(size_t)(16 * nt + l15) * CIN + kc * 32 + q * 8];
            acc[nt] = __builtin_amdgcn_mfma_f32_16x16x32_bf16(af, bf, acc[nt], 0, 0, 0);
        }
    }
#pragma unroll
    for (int nt = 0; nt < 4; nt++) {
        float bias = b1f[16 * nt + l15];
#pragma unroll
        for (int r = 0; r < 4; r++) {
            int px = pxb + 4 * q + r;
            float v = fmaxf(acc[nt][r] + bias, 0.f);
            t_bf[((size_t)b * HW + px) * CR + 16 * nt + l15] = f2bf(v);
        }
    }
}

// k2: fused kernel-gen (MFMA) + involution for one (b, 2-row band, g, cg-half).
// LDS holds ONLY w (22.7 KB). Phase B: tid = (cg*2+row)*16 + quad -> quad in
// low bits => each 16-lane group reads one contiguous, L2-hot x-row segment
// (coalesced); w_lds reads are 2-way/broadcast (free).
__global__ __launch_bounds__(256, 4) void k2_fused(
    const float* __restrict__ x, const unsigned short* __restrict__ t_bf,
    const unsigned short* __restrict__ W2bT, const float* __restrict__ b2,
    float* __restrict__ out)
{
    __shared__ float w_lds[KK * WSTR];               // 22.7 KB

    const int tid = threadIdx.x;
    const int band = blockIdx.x, g = blockIdx.y;
    const int b = blockIdx.z >> 1, half = blockIdx.z & 1;
    const int h0 = band * RB;
    const int lane = tid & 63, l15 = lane & 15, q = lane >> 4;
    const int wid = tid >> 6;

    // ---- phase A: kgen MFMA, M=112 px (7 tiles), N=64 taps, K=64 ----
    {
        short8 bfr[4][2];
#pragma unroll
        for (int nt = 0; nt < 4; nt++)
#pragma unroll
            for (int ks = 0; ks < 2; ks++)
                bfr[nt][ks] = *(const short8*)&W2bT[((size_t)g * 64 + 16 * nt + l15) * 64 + ks * 32 + q * 8];
        float b2v[4];
#pragma unroll
        for (int nt = 0; nt < 4; nt++) {
            int tap = 16 * nt + l15;
            b2v[nt] = (tap < KK) ? b2[g * KK + tap] : 0.f;
        }
        for (int mt = wid; mt < 7; mt += 4) {
            const unsigned short* tp = &t_bf[((size_t)b * HW + h0 * HDIM + mt * 16 + l15) * CR];
            short8 a0 = *(const short8*)&tp[q * 8];
            short8 a1 = *(const short8*)&tp[32 + q * 8];
#pragma unroll
            for (int nt = 0; nt < 4; nt++) {
                f32x4 acc = (f32x4){0.f, 0.f, 0.f, 0.f};
                acc = __builtin_amdgcn_mfma_f32_16x16x32_bf16(a0, bfr[nt][0], acc, 0, 0, 0);
                acc = __builtin_amdgcn_mfma_f32_16x16x32_bf16(a1, bfr[nt][1], acc, 0, 0, 0);
                int tap = 16 * nt + l15;
                if (tap < KK) {
                    *(float4*)&w_lds[tap * WSTR + mt * 16 + 4 * q] =
                        make_float4(acc[0] + b2v[nt], acc[1] + b2v[nt],
                                    acc[2] + b2v[nt], acc[3] + b2v[nt]);
                }
            }
        }
    }
    __syncthreads();

    // ---- phase B: involution; x from global (coalesced), w from LDS ----
    {
        const int quad  = tid & 15;         // 0..13 active
        const int combo = tid >> 4;         // 0..15: cg*2 + row
        if (quad < 14) {
            const int row = combo & 1;
            const int cg  = combo >> 1;
            const int colb = quad * 4;
            const int cb   = colb - 4;      // 12-col window base
            const int h    = h0 + row;
            const bool okL = quad > 0, okR = quad < 13;

            const float* xch = x + ((size_t)b * CIN + g * 16 + half * 8 + cg) * HW;
            const float4 z4 = make_float4(0.f, 0.f, 0.f, 0.f);
            float acc[4] = {0.f, 0.f, 0.f, 0.f};

#pragma unroll
            for (int di = 0; di < 7; di++) {
                int hy = h + di - 3;
                bool rok = (hy >= 0) & (hy < HDIM);
                int hyc = min(max(hy, 0), HDIM - 1);
                const float* xrow = xch + hyc * HDIM;

                float4 A  = (rok && okL) ? *(const float4*)&xrow[cb]     : z4;
                float4 Bv = rok          ? *(const float4*)&xrow[cb + 4] : z4;
                float4 Cv = (rok && okR) ? *(const float4*)&xrow[cb + 8] : z4;
                float win[12] = {A.x, A.y, A.z, A.w, Bv.x, Bv.y, Bv.z, Bv.w,
                                 Cv.x, Cv.y, Cv.z, Cv.w};

                float wv[7][4];
#pragma unroll
                for (int dj = 0; dj < 7; dj++) {
                    float4 wq = *(const float4*)&w_lds[(di * 7 + dj) * WSTR + row * HDIM + colb];
                    wv[dj][0] = wq.x; wv[dj][1] = wq.y; wv[dj][2] = wq.z; wv[dj][3] = wq.w;
                }
#pragma unroll
                for (int dj = 0; dj < 7; dj++)
#pragma unroll
                    for (int kk = 0; kk < 4; kk++)
                        acc[kk] += win[kk + dj + 1] * wv[dj][kk];
            }
            float* op = &out[((size_t)b * CIN + g * 16 + half * 8 + cg) * HW + h * HDIM + colb];
            *(float4*)op = make_float4(acc[0], acc[1], acc[2], acc[3]);
        }
    }
}

extern "C" void kernel_launch(void* const* d_in, const int* in_sizes, int n_in,
                              void* d_out, int out_size, void* d_ws, size_t ws_size,
                              hipStream_t stream) {
    const float* x     = (const float*)d_in[0];
    const float* W1    = (const float*)d_in[1];
    const float* b1    = (const float*)d_in[2];
    const float* gamma = (const float*)d_in[3];
    const float* beta  = (const float*)d_in[4];
    const float* mean  = (const float*)d_in[5];
    const float* var   = (const float*)d_in[6];
    const float* W2    = (const float*)d_in[7];
    const float* b2    = (const float*)d_in[8];
    float* out = (float*)d_out;

    unsigned short* t_bf = (unsigned short*)d_ws;          // 802816 ushorts
    unsigned short* W1b  = t_bf + (size_t)4 * HW * CR;     // 16384
    unsigned short* W2bT = W1b + CR * CIN;                 // 65536
    float* b1f           = (float*)(W2bT + NG * 64 * 64);  // 64

    int n_k0 = CR * CIN + NG * 64 * 64 + CR;
    k0_prep<<<(n_k0 + 255) / 256, 256, 0, stream>>>(
        W1, b1, gamma, beta, mean, var, W2, W1b, W2bT, b1f);

    dim3 g1(HW / 64, 4);
    k1_gemm<<<g1, 256, 0, stream>>>(x, W1b, b1f, t_bf);

    dim3 g2(NBAND, NG, 8);
    k2_fused<<<g2, 256, 0, stream>>>(x, t_bf, W2bT, b2, out);
}

// Round 13
// 132.427 us; speedup vs baseline: 2.7410x; 2.7410x over previous
//
#include <hip/hip_runtime.h>

#define HW    3136
#define HDIM  56
#define CIN   256
#define CR    64
#define NG    16
#define KK    49
#define BEPS  1e-5f
#define RB    2            // output rows per k2 band
#define NBAND 28           // 56 / RB
#define WSTR  116          // w_lds row stride (RB*56 + 4 floats)
#define XROWS 8            // RB + 6 halo rows
#define XSTR  68           // x_lds col stride (56 + 2*4, pre-zeroed borders)
#define XTOT  (XROWS * 8 * XSTR)   // 4352 = 17 * 256 exactly

typedef __attribute__((ext_vector_type(8))) short short8;
typedef __attribute__((ext_vector_type(4))) float f32x4;

__device__ __forceinline__ unsigned short f2bf(float f) {
    union { float f; unsigned u; } v; v.f = f;
    unsigned r = (v.u + 0x7FFFu + ((v.u >> 16) & 1u)) >> 16;
    return (unsigned short)r;
}

// k0: W1b[o][c]=bf16(W1*scale) (B^T for k1); W2bT[g][tap pad64][c]=bf16(W2)
//     (B^T for k2 phase A); b1f = folded BN bias.
__global__ __launch_bounds__(256) void k0_prep(
    const float* __restrict__ W1, const float* __restrict__ b1,
    const float* __restrict__ gamma, const float* __restrict__ beta,
    const float* __restrict__ mean, const float* __restrict__ var,
    const float* __restrict__ W2,
    unsigned short* __restrict__ W1b, unsigned short* __restrict__ W2bT,
    float* __restrict__ b1f)
{
    int idx = blockIdx.x * 256 + threadIdx.x;
    if (idx < CR * CIN) {
        int o = idx >> 8;
        float s = gamma[o] * rsqrtf(var[o] + BEPS);
        W1b[idx] = f2bf(W1[idx] * s);
    } else if (idx < CR * CIN + NG * 64 * 64) {
        int j = idx - CR * CIN;
        int c = j & 63, tap = (j >> 6) & 63, g = j >> 12;
        float v = (tap < KK) ? W2[(g * KK + tap) * CR + c] : 0.f;
        W2bT[j] = f2bf(v);
    } else if (idx < CR * CIN + NG * 64 * 64 + CR) {
        int o = idx - CR * CIN - NG * 64 * 64;
        float s = gamma[o] * rsqrtf(var[o] + BEPS);
        b1f[o] = b1[o] * s + beta[o] - mean[o] * s;
    }
}

// k1: conv1 MFMA, LDS-free (r8-identical). Wave = 16px M-tile x 64 outs, K=256.
__global__ __launch_bounds__(256) void k1_gemm(
    const float* __restrict__ x, const unsigned short* __restrict__ W1b,
    const float* __restrict__ b1f, unsigned short* __restrict__ t_bf)
{
    const int tid = threadIdx.x;
    const int b = blockIdx.y;
    const int lane = tid & 63, l15 = lane & 15, q = lane >> 4;
    const int wid = tid >> 6;
    const int pxb = blockIdx.x * 64 + wid * 16;

    const float* xp = x + (size_t)b * CIN * HW + pxb + l15;

    f32x4 acc[4];
#pragma unroll
    for (int nt = 0; nt < 4; nt++) acc[nt] = (f32x4){0.f, 0.f, 0.f, 0.f};

#pragma unroll 2
    for (int kc = 0; kc < 8; kc++) {
        short8 af;
#pragma unroll
        for (int j = 0; j < 8; j++) {
            float xv = xp[(size_t)(kc * 32 + q * 8 + j) * HW];
            af[j] = (short)f2bf(xv);
        }
#pragma unroll
        for (int nt = 0; nt < 4; nt++) {
            short8 bf = *(const short8*)&W1b[(size_t)(16 * nt + l15) * CIN + kc * 32 + q * 8];
            acc[nt] = __builtin_amdgcn_mfma_f32_16x16x32_bf16(af, bf, acc[nt], 0, 0, 0);
        }
    }
#pragma unroll
    for (int nt = 0; nt < 4; nt++) {
        float bias = b1f[16 * nt + l15];
#pragma unroll
        for (int r = 0; r < 4; r++) {
            int px = pxb + 4 * q + r;
            float v = fmaxf(acc[nt][r] + bias, 0.f);
            t_bf[((size_t)b * HW + px) * CR + 16 * nt + l15] = f2bf(v);
        }
    }
}

// k2: r8 structure — fused kgen (MFMA) + involution for one (b, g, 2-row band,
// cg-half). Only change vs r8: x-staging and phase-A mt loops are compile-time
// unrolled so all global loads issue back-to-back (vmcnt-pipelined) instead of
// serial addr->load->wait chains.
__global__ __launch_bounds__(256, 4) void k2_fused(
    const float* __restrict__ x, const unsigned short* __restrict__ t_bf,
    const unsigned short* __restrict__ W2bT, const float* __restrict__ b2,
    float* __restrict__ out)
{
    __shared__ float w_lds[KK * WSTR];               // 22.7 KB
    __shared__ float x_lds[XTOT];                    // 17.4 KB (40.1 KB total)

    const int tid = threadIdx.x;
    const int band = blockIdx.x, g = blockIdx.y;
    const int b = blockIdx.z >> 1, half = blockIdx.z & 1;
    const int h0 = band * RB;
    const int lane = tid & 63, l15 = lane & 15, q = lane >> 4;
    const int wid = tid >> 6;

    // ---- stage x tile: [rowx][cg 8][col 68], zero-padded borders.
    //      17 full iterations (4352 = 17*256), fully unrolled -> 17 loads in flight.
#pragma unroll
    for (int it = 0; it < 17; it++) {
        int i = it * 256 + tid;
        int col = i % XSTR; int t2 = i / XSTR; int cg = t2 & 7; int rowx = t2 >> 3;
        int hy = h0 - 3 + rowx, xc = col - 4;
        float v = 0.f;
        if (hy >= 0 && hy < HDIM && xc >= 0 && xc < HDIM)
            v = x[((size_t)b * CIN + g * 16 + half * 8 + cg) * HW + hy * HDIM + xc];
        x_lds[i] = v;
    }

    // ---- phase A: kgen MFMA, M=112 px (7 tiles), N=64 taps, K=64 ----
    {
        short8 bfr[4][2];
#pragma unroll
        for (int nt = 0; nt < 4; nt++)
#pragma unroll
            for (int ks = 0; ks < 2; ks++)
                bfr[nt][ks] = *(const short8*)&W2bT[((size_t)g * 64 + 16 * nt + l15) * 64 + ks * 32 + q * 8];
        float b2v[4];
#pragma unroll
        for (int nt = 0; nt < 4; nt++) {
            int tap = 16 * nt + l15;
            b2v[nt] = (tap < KK) ? b2[g * KK + tap] : 0.f;
        }
#pragma unroll
        for (int it = 0; it < 2; it++) {
            int mt = wid + it * 4;
            if (mt < 7) {
                const unsigned short* tp = &t_bf[((size_t)b * HW + h0 * HDIM + mt * 16 + l15) * CR];
                short8 a0 = *(const short8*)&tp[q * 8];
                short8 a1 = *(const short8*)&tp[32 + q * 8];
#pragma unroll
                for (int nt = 0; nt < 4; nt++) {
                    f32x4 acc = (f32x4){0.f, 0.f, 0.f, 0.f};
                    acc = __builtin_amdgcn_mfma_f32_16x16x32_bf16(a0, bfr[nt][0], acc, 0, 0, 0);
                    acc = __builtin_amdgcn_mfma_f32_16x16x32_bf16(a1, bfr[nt][1], acc, 0, 0, 0);
                    int tap = 16 * nt + l15;
                    if (tap < KK) {
                        *(float4*)&w_lds[tap * WSTR + mt * 16 + 4 * q] =
                            make_float4(acc[0] + b2v[nt], acc[1] + b2v[nt],
                                        acc[2] + b2v[nt], acc[3] + b2v[nt]);
                    }
                }
            }
        }
    }
    __syncthreads();

    // ---- phase B: involution. tid = quad*16 + row*8 + cg (r8 mapping) ----
    if (tid < 224) {
        const int quad = tid >> 4;          // 0..13
        const int rem  = tid & 15;
        const int row  = rem >> 3;          // 0..1
        const int cg   = rem & 7;           // 0..7
        const int colb = quad * 4, h = h0 + row;

        float acc[4] = {0.f, 0.f, 0.f, 0.f};

#pragma unroll
        for (int di = 0; di < 7; di++) {
            float wv[7][4];
#pragma unroll
            for (int dj = 0; dj < 7; dj++) {
                float4 wq = *(const float4*)&w_lds[(di * 7 + dj) * WSTR + row * HDIM + colb];
                wv[dj][0] = wq.x; wv[dj][1] = wq.y; wv[dj][2] = wq.z; wv[dj][3] = wq.w;
            }
            const float* xr = &x_lds[((row + di) * 8 + cg) * XSTR + colb];
            float4 A  = *(const float4*)&xr[0];
            float4 Bv = *(const float4*)&xr[4];
            float4 Cv = *(const float4*)&xr[8];
            float win[12] = {A.x, A.y, A.z, A.w, Bv.x, Bv.y, Bv.z, Bv.w,
                             Cv.x, Cv.y, Cv.z, Cv.w};
#pragma unroll
            for (int dj = 0; dj < 7; dj++)
#pragma unroll
                for (int kk = 0; kk < 4; kk++)
                    acc[kk] += win[kk + dj + 1] * wv[dj][kk];
        }
        float* op = &out[((size_t)b * CIN + g * 16 + half * 8 + cg) * HW + h * HDIM + colb];
        *(float4*)op = make_float4(acc[0], acc[1], acc[2], acc[3]);
    }
}

extern "C" void kernel_launch(void* const* d_in, const int* in_sizes, int n_in,
                              void* d_out, int out_size, void* d_ws, size_t ws_size,
                              hipStream_t stream) {
    const float* x     = (const float*)d_in[0];
    const float* W1    = (const float*)d_in[1];
    const float* b1    = (const float*)d_in[2];
    const float* gamma = (const float*)d_in[3];
    const float* beta  = (const float*)d_in[4];
    const float* mean  = (const float*)d_in[5];
    const float* var   = (const float*)d_in[6];
    const float* W2    = (const float*)d_in[7];
    const float* b2    = (const float*)d_in[8];
    float* out = (float*)d_out;

    unsigned short* t_bf = (unsigned short*)d_ws;          // 802816 ushorts
    unsigned short* W1b  = t_bf + (size_t)4 * HW * CR;     // 16384
    unsigned short* W2bT = W1b + CR * CIN;                 // 65536
    float* b1f           = (float*)(W2bT + NG * 64 * 64);  // 64

    int n_k0 = CR * CIN + NG * 64 * 64 + CR;
    k0_prep<<<(n_k0 + 255) / 256, 256, 0, stream>>>(
        W1, b1, gamma, beta, mean, var, W2, W1b, W2bT, b1f);

    dim3 g1(HW / 64, 4);
    k1_gemm<<<g1, 256, 0, stream>>>(x, W1b, b1f, t_bf);

    dim3 g2(NBAND, NG, 8);
    k2_fused<<<g2, 256, 0, stream>>>(x, t_bf, W2bT, b2, out);
}